// Round 4
// baseline (227.603 us; speedup 1.0000x reference)
//
#include <hip/hip_runtime.h>

#define D 64
#define GB_B 16      // b-rows per gamma block
#define MAXS 32

typedef float f32x4 __attribute__((ext_vector_type(4)));

__device__ __forceinline__ float frcp(float x)  { return __builtin_amdgcn_rcpf(x); }
__device__ __forceinline__ float fsq(float x)   { return __builtin_amdgcn_sqrtf(x); }
__device__ __forceinline__ float frsq(float x)  { return __builtin_amdgcn_rsqf(x); }

// ---------------------------------------------------------------------------
// Kernel A: gamma[b][u] = 1 - 0.01*exp(3 * (+-clip(it_norm[b] . u_norm[u])))
// Fused item-row normalization (per-wave shuffle reduce, rows staged in LDS).
// Each thread owns one user row in registers, loops GB_B b-rows.
// inter / gamma accesses fully coalesced.
// ---------------------------------------------------------------------------
__global__ __launch_bounds__(256) void gamma_kernel(
        const float* __restrict__ user_emb,
        const float* __restrict__ item_emb,
        const int*   __restrict__ iids,
        const int*   __restrict__ inter,
        float*       __restrict__ gamma,
        int U, int B) {
    __shared__ float s_it[GB_B * D];     // 4 KB
    const int tid  = threadIdx.x;
    const int lane = tid & 63;
    const int w    = tid >> 6;
    const int b0   = blockIdx.y * GB_B;
    const int nb   = min(GB_B, B - b0);

    // normalize this block's item rows into LDS (wave w handles rows w, w+4,…)
    for (int bb = w; bb < nb; bb += 4) {
        const int row = iids[b0 + bb];
        const float x = item_emb[(size_t)row * D + lane];
        float ss = x * x;
        #pragma unroll
        for (int off = 32; off > 0; off >>= 1)
            ss += __shfl_xor(ss, off, 64);
        s_it[bb * D + lane] = x * frcp(fmaxf(fsq(ss), 1e-12f));
    }

    // this thread's user row (16 float4 = 64 regs)
    const int u  = blockIdx.x * 256 + tid;
    const int uc = (u < U) ? u : (U - 1);
    float4 uv[16];
    const float4* __restrict__ up = (const float4*)(user_emb + (size_t)uc * D);
    #pragma unroll
    for (int j = 0; j < 16; ++j) uv[j] = up[j];

    float ssq = 0.f;
    #pragma unroll
    for (int j = 0; j < 16; ++j)
        ssq += uv[j].x*uv[j].x + uv[j].y*uv[j].y + uv[j].z*uv[j].z + uv[j].w*uv[j].w;
    const float rnorm = frcp(fmaxf(fsq(ssq), 1e-12f));

    __syncthreads();

    // prefetch inter (coalesced, one latency for all GB_B)
    int itv[GB_B];
    #pragma unroll
    for (int bb = 0; bb < GB_B; ++bb)
        itv[bb] = (bb < nb && u < U) ? inter[(size_t)(b0 + bb) * U + u] : 1;

    #pragma unroll
    for (int bb = 0; bb < GB_B; ++bb) {
        if (bb >= nb) break;
        const float4* __restrict__ ip = (const float4*)(s_it + bb * D);
        float d = 0.f;
        #pragma unroll
        for (int j = 0; j < 16; ++j) {
            const float4 iv = ip[j];
            d += uv[j].x*iv.x + uv[j].y*iv.y + uv[j].z*iv.z + uv[j].w*iv.w;
        }
        float score = fminf(fmaxf(d * rnorm, -1.0f), 1.0f);
        if (itv[bb] != 1) score = -score;
        const float gm = 1.0f - 0.01f * __expf(3.0f * score);
        if (u < U) gamma[(size_t)(b0 + bb) * U + u] = gm;
    }
}

// ---------------------------------------------------------------------------
// Kernel B: each (k,s) slab is elementwise in gamma. One block writes a
// contiguous 16 KB chunk of one slab -> chip-wide linear store sweeps,
// slab after slab (mimics the 6.7 TB/s fill pattern). Plain stores.
// Slab m: k=m/S, s=m%S. Slab 5S-1 (acp_next[S-1]) skipped (zeros; may hold
// gamma itself in the no-workspace fallback).
// ---------------------------------------------------------------------------
__device__ __forceinline__ f32x4 slab_val4(f32x4 g, int k, int n,
                                           const float* __restrict__ s_bb,
                                           float bbs) {
    f32x4 r;
    if (k == 0) {                         // sqrt(1/alpha_s), no prefix needed
        for (int e = 0; e < 4; ++e) r[e] = frsq(1.f - g[e] * bbs);
        return r;
    }
    f32x4 ap = {1.f, 1.f, 1.f, 1.f};      // prod_{t<n} (1-g*bb[t]) = acp_{n-1}
    for (int t = 0; t < n; ++t) {
        const float bbt = s_bb[t];
        for (int e = 0; e < 4; ++e) ap[e] *= (1.f - g[e] * bbt);
    }
    const float bbn = s_bb[n];
    f32x4 acp;                            // acp_n
    for (int e = 0; e < 4; ++e) acp[e] = ap[e] * (1.f - g[e] * bbn);

    if (k == 1) {
        r = acp;                                          // alphas_cumprod
    } else if (k == 2) {
        for (int e = 0; e < 4; ++e) r[e] = fsq(1.f - acp[e]);
    } else if (k == 3) {
        r = ap;                                           // acp_prev
    } else if (k == 4) {
        r = acp;                                          // acp_next (n=s+1)
    } else if (k == 5) {
        for (int e = 0; e < 4; ++e) r[e] = fsq(acp[e]);
    } else if (k == 6) {
        for (int e = 0; e < 4; ++e) r[e] = __logf(1.f - acp[e]);
    } else if (k == 7) {
        for (int e = 0; e < 4; ++e) r[e] = frsq(acp[e]);
    } else if (k == 8) {
        for (int e = 0; e < 4; ++e) r[e] = fsq(1.f - acp[e]) * frsq(acp[e]);
    } else if (k == 9) {
        for (int e = 0; e < 4; ++e) r[e] = g[e]*bbs * fsq(ap[e]) * frcp(1.f - acp[e]);
    } else if (k == 10) {
        for (int e = 0; e < 4; ++e) r[e] = (1.f - ap[e]) * fsq(1.f - g[e]*bbs) * frcp(1.f - acp[e]);
    } else if (k == 11) {
        for (int e = 0; e < 4; ++e) r[e] = fsq(1.f - ap[e]) * frsq(1.f - acp[e]);
    } else if (k == 12) {
        for (int e = 0; e < 4; ++e) r[e] = fsq(acp[e]) * fsq(1.f - ap[e]) * frsq(1.f - acp[e]);
    } else {
        for (int e = 0; e < 4; ++e) r[e] = g[e]*bbs * (1.f - ap[e]) * frcp(1.f - acp[e]); // 13
    }
    return r;
}

__global__ __launch_bounds__(256) void slab_kernel(
        const float* __restrict__ gamma,
        const float* __restrict__ base_betas,
        float*       __restrict__ out,
        int S, size_t BU) {
    __shared__ float s_bb[MAXS];
    const int tid = threadIdx.x;
    if (tid < S) s_bb[tid] = base_betas[tid];
    __syncthreads();

    int m = blockIdx.y;
    const int skip = 5 * S - 1;           // slab (k=4, s=S-1): constant zeros
    if (m >= skip) ++m;
    const int k = m / S;
    const int s = m - k * S;
    const int n = (k == 4) ? s + 1 : s;   // k==4: store acp_{s+1}
    const float bbs = s_bb[s];

    float* __restrict__ op = out + (size_t)m * BU;

    #pragma unroll
    for (int it = 0; it < 4; ++it) {
        const size_t v  = (size_t)blockIdx.x * 1024 + (size_t)it * 256 + tid;
        const size_t f0 = v * 4;
        if (f0 + 4 <= BU) {
            const f32x4 gv = *(const f32x4*)(gamma + f0);
            const f32x4 val = slab_val4(gv, k, n, s_bb, bbs);
            *(f32x4*)(op + f0) = val;
        } else if (f0 < BU) {
            for (size_t f = f0; f < BU; ++f) {
                f32x4 gv = {gamma[f], 0.f, 0.f, 0.f};
                const f32x4 val = slab_val4(gv, k, n, s_bb, bbs);
                op[f] = val[0];
            }
        }
    }
}

// ---------------------------------------------------------------------------
// Kernel C: acp_next[S-1] = 0. Launched AFTER slab_kernel so the
// gamma-in-output fallback is race-free by stream ordering.
// ---------------------------------------------------------------------------
__global__ __launch_bounds__(256) void zero_slab_kernel(float* __restrict__ p,
                                                        size_t n) {
    const size_t f0 = ((size_t)blockIdx.x * blockDim.x + threadIdx.x) * 4;
    if (f0 + 4 <= n) {
        f32x4 z = {0.f, 0.f, 0.f, 0.f};
        *(f32x4*)(p + f0) = z;
    } else {
        for (size_t f = f0; f < n; ++f) p[f] = 0.f;
    }
}

extern "C" void kernel_launch(void* const* d_in, const int* in_sizes, int n_in,
                              void* d_out, int out_size, void* d_ws, size_t ws_size,
                              hipStream_t stream) {
    const float* user_emb   = (const float*)d_in[0];   // [U, 64]
    const float* item_emb   = (const float*)d_in[1];   // [I, 64]
    const int*   iids       = (const int*)d_in[2];     // [B]
    const int*   inter      = (const int*)d_in[3];     // [B, U]
    const float* base_betas = (const float*)d_in[4];   // [S]

    const int U = in_sizes[0] / D;
    const int B = in_sizes[2];
    const int S = in_sizes[4];

    float* out = (float*)d_out;
    const size_t BU = (size_t)B * U;

    // gamma: workspace if it fits, else the (constant-zero) acp_next[S-1] slab
    float* gamma = (ws_size >= BU * sizeof(float))
                 ? (float*)d_ws
                 : out + (size_t)(5 * S - 1) * BU;

    dim3 ga((U + 255) / 256, (B + GB_B - 1) / GB_B);
    gamma_kernel<<<ga, 256, 0, stream>>>(user_emb, item_emb, iids, inter,
                                         gamma, U, B);

    const int chunks = (int)((BU / 4 + 1023) / 1024);
    dim3 gb(chunks, 14 * S - 1);
    slab_kernel<<<gb, 256, 0, stream>>>(gamma, base_betas, out, S, BU);

    zero_slab_kernel<<<(int)((BU + 1023) / 1024), 256, 0, stream>>>(
        out + (size_t)(5 * S - 1) * BU, BU);
}

// Round 5
// 152.772 us; speedup vs baseline: 1.4898x; 1.4898x over previous
//
#include <hip/hip_runtime.h>

#define D 64
#define GB_B 8       // b-rows per gamma block
#define MAXS 32

typedef float f32x4 __attribute__((ext_vector_type(4)));

__device__ __forceinline__ float frcp(float x)  { return __builtin_amdgcn_rcpf(x); }
__device__ __forceinline__ float fsq(float x)   { return __builtin_amdgcn_sqrtf(x); }
__device__ __forceinline__ float frsq(float x)  { return __builtin_amdgcn_rsqf(x); }

// ---------------------------------------------------------------------------
// Kernel A: gamma[b][u] = 1 - 0.01*exp(3 * (+-clip(it_norm[b] . u_norm[u])))
// Fused item-row normalization; user row register-resident; all global
// accesses coalesced. (Verified correct in R4.)
// ---------------------------------------------------------------------------
__global__ __launch_bounds__(256) void gamma_kernel(
        const float* __restrict__ user_emb,
        const float* __restrict__ item_emb,
        const int*   __restrict__ iids,
        const int*   __restrict__ inter,
        float*       __restrict__ gamma,
        int U, int B) {
    __shared__ float s_it[GB_B * D];     // 2 KB
    const int tid  = threadIdx.x;
    const int lane = tid & 63;
    const int w    = tid >> 6;
    const int b0   = blockIdx.y * GB_B;
    const int nb   = min(GB_B, B - b0);

    // normalize this block's item rows into LDS (wave w handles rows w, w+4,…)
    for (int bb = w; bb < nb; bb += 4) {
        const int row = iids[b0 + bb];
        const float x = item_emb[(size_t)row * D + lane];
        float ss = x * x;
        #pragma unroll
        for (int off = 32; off > 0; off >>= 1)
            ss += __shfl_xor(ss, off, 64);
        s_it[bb * D + lane] = x * frcp(fmaxf(fsq(ss), 1e-12f));
    }

    // this thread's user row (16 float4)
    const int u  = blockIdx.x * 256 + tid;
    const int uc = (u < U) ? u : (U - 1);
    float4 uv[16];
    const float4* __restrict__ up = (const float4*)(user_emb + (size_t)uc * D);
    #pragma unroll
    for (int j = 0; j < 16; ++j) uv[j] = up[j];

    float ssq = 0.f;
    #pragma unroll
    for (int j = 0; j < 16; ++j)
        ssq += uv[j].x*uv[j].x + uv[j].y*uv[j].y + uv[j].z*uv[j].z + uv[j].w*uv[j].w;
    const float rnorm = frcp(fmaxf(fsq(ssq), 1e-12f));

    __syncthreads();

    // prefetch inter (coalesced)
    int itv[GB_B];
    #pragma unroll
    for (int bb = 0; bb < GB_B; ++bb)
        itv[bb] = (bb < nb && u < U) ? inter[(size_t)(b0 + bb) * U + u] : 1;

    #pragma unroll
    for (int bb = 0; bb < GB_B; ++bb) {
        if (bb >= nb) break;
        const float4* __restrict__ ip = (const float4*)(s_it + bb * D);
        float d = 0.f;
        #pragma unroll
        for (int j = 0; j < 16; ++j) {
            const float4 iv = ip[j];
            d += uv[j].x*iv.x + uv[j].y*iv.y + uv[j].z*iv.z + uv[j].w*iv.w;
        }
        float score = fminf(fmaxf(d * rnorm, -1.0f), 1.0f);
        if (itv[bb] != 1) score = -score;
        const float gm = 1.0f - 0.01f * __expf(3.0f * score);
        if (u < U) gamma[(size_t)(b0 + bb) * U + u] = gm;
    }
}

// ---------------------------------------------------------------------------
// Kernel B: pure store machine over flat p = b*U+u. gamma read ONCE per
// thread; per s-step exactly 14 aligned nt stores (acp_next computed one
// step ahead, so no lagged stream and no zero pass). Raw s_barrier each
// step paces waves so the chip stays within one slab-step window.
// ---------------------------------------------------------------------------
__global__ __launch_bounds__(256) void store_kernel(
        const float* __restrict__ gamma,
        const float* __restrict__ base_betas,
        float*       __restrict__ out,
        int S, size_t P) {                 // P = B*U
    __shared__ float s_bb[MAXS];
    if (threadIdx.x < S) s_bb[threadIdx.x] = base_betas[threadIdx.x];
    __syncthreads();

    const size_t p = ((size_t)blockIdx.x * 256 + threadIdx.x) * 4;
    if (p >= P) return;
    const bool full = (p + 4 <= P);

    f32x4 g;
    if (full) {
        g = *(const f32x4*)(gamma + p);
    } else {
        for (int e = 0; e < 4; ++e)
            g[e] = (p + e < P) ? gamma[p + e] : 1.0f;
    }

    const size_t BU  = P;
    const size_t SBU = (size_t)S * BU;
    float* __restrict__ o = out + p;

    f32x4 acp; for (int e = 0; e < 4; ++e) acp[e] = 1.0f;

    #define STV(k, val)                                                       \
        do {                                                                  \
            float* _p = o + (size_t)(k) * SBU + soff;                         \
            if (full) __builtin_nontemporal_store((val), (f32x4*)_p);         \
            else {                                                            \
                for (int _c = 0; _c < 4; ++_c)                                \
                    if (p + _c < P) _p[_c] = (val)[_c];                       \
            }                                                                 \
        } while (0)

    for (int s = 0; s < S; ++s) {
        const float bbs  = s_bb[s];
        const float bbn  = (s + 1 < S) ? s_bb[s + 1] : 0.0f;
        const size_t soff = (size_t)s * BU;

        f32x4 aprev = acp;
        f32x4 beta, a, om, rc, so, sa, rsa, srA, sqA, lom, anext;
        f32x4 omp, sapp, f2a, t8, t9, t10, t12, t13;
        for (int e = 0; e < 4; ++e) {
            const float bt = g[e] * bbs;
            const float al = 1.0f - bt;
            const float av = aprev[e] * al;
            beta[e] = bt;
            a[e]    = av;
            om[e]   = 1.0f - av;
            rc[e]   = frcp(om[e]);
            so[e]   = fsq(om[e]);
            sa[e]   = fsq(av);
            rsa[e]  = frsq(av);
            srA[e]  = frsq(al);
            sqA[e]  = al * srA[e];
            lom[e]  = __logf(om[e]);
            anext[e] = (s + 1 < S) ? av * (1.0f - g[e] * bbn) : 0.0f;
            omp[e]  = 1.0f - aprev[e];       // 1 - acp_prev
            sapp[e] = fsq(aprev[e]);         // sqrt(acp_prev)
            f2a[e]  = fsq(omp[e]) * frcp(so[e]);  // sqrt(1-acp_prev)/sqrt(1-acp)
            t8[e]   = so[e] * rsa[e];
            t9[e]   = beta[e] * sapp[e] * rc[e];
            t10[e]  = omp[e] * sqA[e] * rc[e];
            t12[e]  = sa[e] * f2a[e];
            t13[e]  = beta[e] * omp[e] * rc[e];
        }

        STV(0,  srA);    // sqrt_recip_alphas
        STV(1,  a);      // alphas_cumprod
        STV(2,  so);     // sqrt_one_minus_acp
        STV(3,  aprev);  // acp_prev
        STV(4,  anext);  // acp_next
        STV(5,  sa);     // sqrt_acp
        STV(6,  lom);    // log_one_minus_acp
        STV(7,  rsa);    // sqrt_recip_acp
        STV(8,  t8);     // sqrt_recipm1_acp
        STV(9,  t9);     // posterior_mean_coef1
        STV(10, t10);    // posterior_mean_coef2
        STV(11, f2a);    // fast_posterior_coef2
        STV(12, t12);    // fast_posterior_coef3
        STV(13, t13);    // posterior_variance

        acp = a;
        __builtin_amdgcn_s_barrier();   // pacing only: no data dependence
    }
    #undef STV
}

extern "C" void kernel_launch(void* const* d_in, const int* in_sizes, int n_in,
                              void* d_out, int out_size, void* d_ws, size_t ws_size,
                              hipStream_t stream) {
    const float* user_emb   = (const float*)d_in[0];   // [U, 64]
    const float* item_emb   = (const float*)d_in[1];   // [I, 64]
    const int*   iids       = (const int*)d_in[2];     // [B]
    const int*   inter      = (const int*)d_in[3];     // [B, U]
    const float* base_betas = (const float*)d_in[4];   // [S]

    const int U = in_sizes[0] / D;
    const int B = in_sizes[2];
    const int S = in_sizes[4];

    float* out = (float*)d_out;
    const size_t P = (size_t)B * U;

    // gamma: workspace if it fits, else the acp_next[S-1] slab of out
    // (store_kernel thread reads gamma[p] before overwriting that address
    //  with 0 at s=S-1 — same-thread ordering, race-free).
    float* gamma = (ws_size >= P * sizeof(float))
                 ? (float*)d_ws
                 : out + (size_t)(5 * S - 1) * P;

    dim3 ga((U + 255) / 256, (B + GB_B - 1) / GB_B);
    gamma_kernel<<<ga, 256, 0, stream>>>(user_emb, item_emb, iids, inter,
                                         gamma, U, B);

    const int blocks = (int)((P / 4 + 255) / 256);
    store_kernel<<<blocks, 256, 0, stream>>>(gamma, base_betas, out, S, P);
}